// Round 8
// baseline (11702.958 us; speedup 1.0000x reference)
//
#include <hip/hip_runtime.h>
#include <cmath>

// R8: layer-pipelined wavefront LSTM. 176 persistent blocks = 11 layers x 16
// rowgroups (16 batch rows each). Sequential depth drops 5632 -> ~523 steps.
// Inter-layer X passed through ring buffers in d_ws with agent-scope atomics
// (cross-XCD safe). MFMA 16x16x32 f16, M=16 real batch rows, 27 N-tiles,
// 14 waves x 2 tiles. u=[x:128|h:128] f16 in LDS, stride 264 (bank-clean).

namespace {
constexpr int H = 106, G4 = 424, SEQ = 512, BB = 256;
constexpr int KIN0 = 100;
constexpr int UST = 264;            // u row stride (f16); 132 dwords
constexpr int GST = 436;            // gates row stride (f32)
constexpr int NTHR = 896;           // 14 waves
constexpr int RGN = 16;             // rowgroups (16 rows each)
constexpr int NLAYER = 11;
constexpr int RING_D = 16;          // ring depth in steps
constexpr int ROW_DW = 56;          // 112 f16 per ring row = 56 dwords
constexpr size_t CNT_STRIDE = 16;   // dwords per counter (64B padded)
constexpr size_t PROD_OFF = 0;          // dword offsets in ws
constexpr size_t CONS_OFF = 8192;
constexpr size_t RING_OFF = 16384;      // 64KB
constexpr size_t RING_PER_L = (size_t)RING_D * BB * ROW_DW;

using f16x8 = __attribute__((ext_vector_type(8))) _Float16;
using f32x4 = __attribute__((ext_vector_type(4))) float;

__device__ __forceinline__ void spin_ge(const unsigned* p, unsigned tgt) {
    while (__hip_atomic_load(p, __ATOMIC_ACQUIRE, __HIP_MEMORY_SCOPE_AGENT) < tgt)
        __builtin_amdgcn_s_sleep(4);
}
__device__ __forceinline__ float fast_tanh(float x) {
    float t = __expf(2.0f * x);
    return 1.0f - 2.0f / (t + 1.0f);
}
__device__ __forceinline__ float act_gate(float g, bool istanh) {
    float s = istanh ? 2.0f * g : g;
    float r = 1.0f / (1.0f + __expf(-s));
    return istanh ? 2.0f * r - 1.0f : r;
}
__device__ __forceinline__ unsigned packh2(float a, float b) {
    unsigned lo = (unsigned)__builtin_bit_cast(unsigned short, (_Float16)a);
    unsigned hi = (unsigned)__builtin_bit_cast(unsigned short, (_Float16)b);
    return (hi << 16) | lo;
}

__global__ __launch_bounds__(NTHR)
__attribute__((amdgpu_waves_per_eu(4, 4)))
void lstm_wave(const float* __restrict__ noise,   // (512,256,100) f32
               float* __restrict__ yout,          // (512,256,106) f32
               unsigned* ws_dw,
               const float* __restrict__ W_ih0, const float* __restrict__ W_hh0,
               const float* __restrict__ b_ih0, const float* __restrict__ b_hh0,
               const float* __restrict__ W_ih,  const float* __restrict__ W_hh,
               const float* __restrict__ b_ih,  const float* __restrict__ b_hh)
{
    // block decode: all 11 layers of a rowgroup-pair land on one XCD (perf only)
    const int xcd = blockIdx.x & 7, jj = blockIdx.x >> 3;
    const int l  = jj >> 1;
    const int rg = 2 * xcd + (jj & 1);
    const bool LAST = (l == NLAYER - 1);
    const int K_IN = (l == 0) ? KIN0 : H;

    const float* Wih = (l == 0) ? W_ih0 : W_ih + (size_t)(l - 1) * G4 * H;
    const float* Whh = (l == 0) ? W_hh0 : W_hh + (size_t)(l - 1) * G4 * H;
    const float* pbi = (l == 0) ? b_ih0 : b_ih + (size_t)(l - 1) * G4;
    const float* pbh = (l == 0) ? b_hh0 : b_hh + (size_t)(l - 1) * G4;

    unsigned* prod_my = ws_dw + PROD_OFF + (size_t)(l * RGN + rg) * CNT_STRIDE;
    unsigned* cons_my = ws_dw + CONS_OFF + (size_t)(l * RGN + rg) * CNT_STRIDE;
    const unsigned* prod_in = ws_dw + PROD_OFF + (size_t)((l - 1) * RGN + rg) * CNT_STRIDE;
    unsigned* cons_in = ws_dw + CONS_OFF + (size_t)((l - 1) * RGN + rg) * CNT_STRIDE;
    unsigned* ring_in  = ws_dw + RING_OFF + (size_t)(l - 1) * RING_PER_L;
    unsigned* ring_out = ws_dw + RING_OFF + (size_t)l * RING_PER_L;

    __shared__ __align__(16) _Float16 su[16 * UST];   // [x:0..127 | h:128..233 | pad]
    __shared__ float gl[16 * GST];

    const int tid = threadIdx.x;
    const int w = tid >> 6, lane = tid & 63;
    const int l16 = lane & 15, kg = lane >> 4;
    const int lm = tid / 56, ld = tid % 56;           // loader map (row, dword)

    // ---- weights: 2 N-tiles/wave, 8 k-steps, packed f16x8 fragments ----
    f16x8 bf[2][8];
    float bias[2];
    #pragma unroll
    for (int t = 0; t < 2; ++t) {
        const int n = 16 * (2 * w + t) + l16;
        const bool valid = n < G4;
        const float* pwx = Wih + (size_t)(valid ? n : 0) * K_IN;
        const float* pwh = Whh + (size_t)(valid ? n : 0) * H;
        #pragma unroll
        for (int q = 0; q < 8; ++q) {
            f16x8 v;
            #pragma unroll
            for (int e = 0; e < 8; ++e) {
                const int k = 32 * q + 8 * kg + e;
                float f = 0.0f;
                if (valid) {
                    if (k < 128) { if (k < K_IN) f = pwx[k]; }
                    else { const int kh = k - 128; if (kh < H) f = pwh[kh]; }
                }
                v[e] = (_Float16)f;
            }
            bf[t][q] = v;
        }
        bias[t] = valid ? (pbi[n] + pbh[n]) : 0.0f;
    }

    // ---- init: zero u, load x_0 ----
    for (int i = tid; i < 16 * (UST / 2); i += NTHR) ((unsigned*)su)[i] = 0;
    float c0 = 0.0f, c1 = 0.0f;
    __syncthreads();
    {
        unsigned xr = 0;
        if (l == 0) {
            if (ld < 50) {
                const float2 v = *(const float2*)(noise + ((size_t)0 * BB + rg * 16 + lm) * KIN0 + 2 * ld);
                xr = packh2(v.x, v.y);
            }
        } else {
            spin_ge(prod_in, 1u);
            xr = __hip_atomic_load(ring_in + ((size_t)(0 % RING_D) * BB + rg * 16 + lm) * ROW_DW + ld,
                                   __ATOMIC_RELAXED, __HIP_MEMORY_SCOPE_AGENT);
        }
        ((unsigned*)su)[lm * 132 + ld] = xr;
    }
    __syncthreads();

    const _Float16* abase = su + (size_t)l16 * UST + 8 * kg;
    const int um = tid / 53, up = tid % 53;           // update map (row, pair)

    for (int s = 0; s < SEQ; ++s) {
        // phase a: fetch x_{s+1} into regs (spin rarely; latency hidden below)
        unsigned xr = 0;
        if (s + 1 < SEQ) {
            if (l == 0) {
                if (ld < 50) {
                    const float2 v = *(const float2*)(noise + ((size_t)(s + 1) * BB + rg * 16 + lm) * KIN0 + 2 * ld);
                    xr = packh2(v.x, v.y);
                }
            } else {
                spin_ge(prod_in, (unsigned)(s + 2));
                xr = __hip_atomic_load(ring_in + ((size_t)((s + 1) % RING_D) * BB + rg * 16 + lm) * ROW_DW + ld,
                                       __ATOMIC_RELAXED, __HIP_MEMORY_SCOPE_AGENT);
            }
        }
        if (tid == 0 && !LAST && s >= RING_D) spin_ge(cons_my, (unsigned)(s - RING_D + 1));

        // phase b: x-part MFMAs (read u.x = x_s)
        f32x4 acc[2] = {{0, 0, 0, 0}, {0, 0, 0, 0}};
        #pragma unroll
        for (int q = 0; q < 4; ++q) {
            const f16x8 a = *(const f16x8*)(abase + 32 * q);
            acc[0] = __builtin_amdgcn_mfma_f32_16x16x32_f16(a, bf[0][q], acc[0], 0, 0, 0);
            acc[1] = __builtin_amdgcn_mfma_f32_16x16x32_f16(a, bf[1][q], acc[1], 0, 0, 0);
        }
        __syncthreads();   // barrier X: x_s reads done

        // phase e: h-part MFMAs (read u.h = h_{s-1})
        #pragma unroll
        for (int q = 4; q < 8; ++q) {
            const f16x8 a = *(const f16x8*)(abase + 32 * q);
            acc[0] = __builtin_amdgcn_mfma_f32_16x16x32_f16(a, bf[0][q], acc[0], 0, 0, 0);
            acc[1] = __builtin_amdgcn_mfma_f32_16x16x32_f16(a, bf[1][q], acc[1], 0, 0, 0);
        }
        // phase f: activation + gates to LDS. C map: row=4*kg+r, col=l16.
        #pragma unroll
        for (int t = 0; t < 2; ++t) {
            const int n = 16 * (2 * w + t) + l16;
            if (n < G4) {
                const bool istanh = (n >= 2 * H) && (n < 3 * H);
                #pragma unroll
                for (int r = 0; r < 4; ++r) {
                    const int m = 4 * kg + r;
                    gl[m * GST + n] = act_gate(acc[t][r] + bias[t], istanh);
                }
            }
        }
        // phase d: install x_{s+1} (x_s reads completed at barrier X)
        if (s + 1 < SEQ) ((unsigned*)su)[lm * 132 + ld] = xr;
        __syncthreads();   // barrier G: gates + x install + h reads done

        // phase h: state update + publish
        if (tid < 848) {
            const float* gm = gl + um * GST;
            const float i0 = gm[2 * up],          i1 = gm[2 * up + 1];
            const float f0 = gm[H + 2 * up],      f1 = gm[H + 2 * up + 1];
            const float g0 = gm[2 * H + 2 * up],  g1 = gm[2 * H + 2 * up + 1];
            const float o0 = gm[3 * H + 2 * up],  o1 = gm[3 * H + 2 * up + 1];
            c0 = fmaf(f0, c0, i0 * g0);
            c1 = fmaf(f1, c1, i1 * g1);
            const float h0 = o0 * fast_tanh(c0);
            const float h1 = o1 * fast_tanh(c1);
            const unsigned hw = packh2(h0, h1);
            ((unsigned*)su)[um * 132 + 64 + up] = hw;       // u.h col 128+2p
            if (LAST) {
                *(float2*)(yout + ((size_t)s * BB + rg * 16 + um) * H + 2 * up) =
                    make_float2(h0, h1);
            } else {
                __hip_atomic_store(ring_out + ((size_t)(s % RING_D) * BB + rg * 16 + um) * ROW_DW + up,
                                   hw, __ATOMIC_RELAXED, __HIP_MEMORY_SCOPE_AGENT);
            }
        } else if (!LAST) {   // ring pad dwords 53..55 (cols 106..111) = 0
            const int t2 = tid - 848, m = t2 / 3, dd = t2 % 3;
            __hip_atomic_store(ring_out + ((size_t)(s % RING_D) * BB + rg * 16 + m) * ROW_DW + 53 + dd,
                               0u, __ATOMIC_RELAXED, __HIP_MEMORY_SCOPE_AGENT);
        }
        __syncthreads();   // barrier U: u=[x_{s+1}|h_s], ring writes complete

        if (tid == 0 && !LAST)
            __hip_atomic_store(prod_my, (unsigned)(s + 1),
                               __ATOMIC_RELEASE, __HIP_MEMORY_SCOPE_AGENT);
        if (tid == 1 && l > 0 && s + 1 < SEQ)
            __hip_atomic_store(cons_in, (unsigned)(s + 2),
                               __ATOMIC_RELEASE, __HIP_MEMORY_SCOPE_AGENT);
    }
}
}  // namespace

extern "C" void kernel_launch(void* const* d_in, const int* in_sizes, int n_in,
                              void* d_out, int out_size, void* d_ws, size_t ws_size,
                              hipStream_t stream) {
    const float* noise = (const float*)d_in[0];
    const float* W_ih0 = (const float*)d_in[1];
    const float* W_hh0 = (const float*)d_in[2];
    const float* b_ih0 = (const float*)d_in[3];
    const float* b_hh0 = (const float*)d_in[4];
    const float* W_ih  = (const float*)d_in[5];
    const float* W_hh  = (const float*)d_in[6];
    const float* b_ih  = (const float*)d_in[7];
    const float* b_hh  = (const float*)d_in[8];

    // zero the producer/consumer counters (first 64KB of ws) every call
    hipMemsetAsync(d_ws, 0, 65536, stream);

    lstm_wave<<<dim3(NLAYER * RGN), dim3(NTHR), 0, stream>>>(
        noise, (float*)d_out, (unsigned*)d_ws,
        W_ih0, W_hh0, b_ih0, b_hh0, W_ih, W_hh, b_ih, b_hh);
}

// Round 9
// 1476.297 us; speedup vs baseline: 7.9272x; 7.9272x over previous
//
#include <hip/hip_runtime.h>
#include <cmath>

// R9: layer-pipelined wavefront LSTM, cross-block handoff FIXED.
// R8 failed because acquire/release at agent scope = L2 writeback+invalidate
// per step (427MB WRITE_SIZE). R9 uses RELAXED-ONLY atomics (bypass to IC, no
// flushes): each ring element is u64 (tag=step+1 | h2-payload), consumer polls
// its own element's tag. Backpressure via relaxed consumer counter. Rings and
// counters memset per call (replay-safe). Compute structure = R8 (HW-validated:
// passed with absmax 4.88e-4). 176 blocks = 11 layers x 16 rowgroups, M=16.

namespace {
constexpr int H = 106, G4 = 424, SEQ = 512, BB = 256, KIN0 = 100;
constexpr int UST = 264;            // u row stride (f16); 132 dwords
constexpr int GST = 436;            // gates row stride (f32)
constexpr int NTHR = 896;           // 14 waves
constexpr int RGN = 16;             // rowgroups (16 rows each)
constexpr int NLAYER = 11;
constexpr int RD = 8;               // ring depth (steps)
constexpr int REL = 56;             // u64 elements per ring row
constexpr size_t CNT_STRIDE = 16;   // dwords per counter (64B)
constexpr size_t RING_OFF_B = 65536;
constexpr size_t RING_PER_L = (size_t)RD * BB * REL;   // u64 elements

using f16x8 = __attribute__((ext_vector_type(8))) _Float16;
using f32x4 = __attribute__((ext_vector_type(4))) float;
typedef unsigned long long u64;

__device__ __forceinline__ u64 ald(const u64* p) {
    return __hip_atomic_load(p, __ATOMIC_RELAXED, __HIP_MEMORY_SCOPE_AGENT);
}
__device__ __forceinline__ void ast(u64* p, u64 v) {
    __hip_atomic_store(p, v, __ATOMIC_RELAXED, __HIP_MEMORY_SCOPE_AGENT);
}
__device__ __forceinline__ void spinc(const unsigned* p, unsigned tgt) {
    while (__hip_atomic_load(p, __ATOMIC_RELAXED, __HIP_MEMORY_SCOPE_AGENT) < tgt)
        __builtin_amdgcn_s_sleep(8);
}
__device__ __forceinline__ float fast_tanh(float x) {
    float t = __expf(2.0f * x);
    return 1.0f - 2.0f / (t + 1.0f);
}
__device__ __forceinline__ float act_gate(float g, bool istanh) {
    float s = istanh ? 2.0f * g : g;
    float r = 1.0f / (1.0f + __expf(-s));
    return istanh ? 2.0f * r - 1.0f : r;
}
__device__ __forceinline__ unsigned packh2(float a, float b) {
    unsigned lo = (unsigned)__builtin_bit_cast(unsigned short, (_Float16)a);
    unsigned hi = (unsigned)__builtin_bit_cast(unsigned short, (_Float16)b);
    return (hi << 16) | lo;
}

__global__ __launch_bounds__(NTHR)
__attribute__((amdgpu_waves_per_eu(4, 4)))   // caps 1 block/CU (14+14 waves won't fit)
void lstm_wave(const float* __restrict__ noise,   // (512,256,100) f32
               float* __restrict__ yout,          // (512,256,106) f32
               unsigned* cnt, u64* ring,
               const float* __restrict__ W_ih0, const float* __restrict__ W_hh0,
               const float* __restrict__ b_ih0, const float* __restrict__ b_hh0,
               const float* __restrict__ W_ih,  const float* __restrict__ W_hh,
               const float* __restrict__ b_ih,  const float* __restrict__ b_hh)
{
    const int l = blockIdx.x / RGN;
    const int rg = blockIdx.x % RGN;
    const bool LAST = (l == NLAYER - 1);
    const int K_IN = (l == 0) ? KIN0 : H;

    const float* Wih = (l == 0) ? W_ih0 : W_ih + (size_t)(l - 1) * G4 * H;
    const float* Whh = (l == 0) ? W_hh0 : W_hh + (size_t)(l - 1) * G4 * H;
    const float* pbi = (l == 0) ? b_ih0 : b_ih + (size_t)(l - 1) * G4;
    const float* pbh = (l == 0) ? b_hh0 : b_hh + (size_t)(l - 1) * G4;

    // cons counter (l-1,rg): written by layer l (consumer), read by l-1 (producer)
    unsigned* cons_my = cnt + (size_t)(l * RGN + rg) * CNT_STRIDE;
    unsigned* cons_in = cnt + (size_t)((l - 1) * RGN + rg) * CNT_STRIDE;
    u64* ring_in  = ring + (size_t)(l - 1) * RING_PER_L;
    u64* ring_out = ring + (size_t)l * RING_PER_L;

    __shared__ __align__(16) _Float16 su[16 * UST];   // [x:0..127 | h:128..233 | pad]
    __shared__ float gl[16 * GST];

    const int tid = threadIdx.x;
    const int w = tid >> 6, lane = tid & 63;
    const int l16 = lane & 15, kg = lane >> 4;
    const int lm = tid / 56, ld = tid % 56;   // loader map (row, element)

    // ---- weights: 2 N-tiles/wave, 8 k-steps (HW-validated in R8) ----
    f16x8 bf[2][8];
    float bias[2];
    #pragma unroll
    for (int t = 0; t < 2; ++t) {
        const int n = 16 * (2 * w + t) + l16;
        const bool valid = n < G4;
        const float* pwx = Wih + (size_t)(valid ? n : 0) * K_IN;
        const float* pwh = Whh + (size_t)(valid ? n : 0) * H;
        #pragma unroll
        for (int q = 0; q < 8; ++q) {
            f16x8 v;
            #pragma unroll
            for (int e = 0; e < 8; ++e) {
                const int k = 32 * q + 8 * kg + e;
                float f = 0.0f;
                if (valid) {
                    if (k < 128) { if (k < K_IN) f = pwx[k]; }
                    else { const int kh = k - 128; if (kh < H) f = pwh[kh]; }
                }
                v[e] = (_Float16)f;
            }
            bf[t][q] = v;
        }
        bias[t] = valid ? (pbi[n] + pbh[n]) : 0.0f;
    }

    // ---- init: zero u, fetch x_0 (tag 1) ----
    for (int i = tid; i < 16 * (UST / 2); i += NTHR) ((unsigned*)su)[i] = 0;
    float c0 = 0.0f, c1 = 0.0f;
    __syncthreads();
    {
        unsigned xr = 0;
        if (l == 0) {
            if (ld < 50) {
                const float2 v = *(const float2*)(noise + ((size_t)rg * 16 + lm) * KIN0 + 2 * ld);
                xr = packh2(v.x, v.y);
            }
        } else {
            const u64* p = ring_in + ((size_t)0 * BB + rg * 16 + lm) * REL + ld;
            u64 v = ald(p);
            while ((unsigned)(v >> 32) != 1u) { __builtin_amdgcn_s_sleep(1); v = ald(p); }
            xr = (unsigned)v;
        }
        ((unsigned*)su)[lm * 132 + ld] = xr;
    }
    __syncthreads();

    const _Float16* abase = su + (size_t)l16 * UST + 8 * kg;
    const int um = tid / 53, up = tid % 53;   // update map (row, H-pair)

    for (int s = 0; s < SEQ; ++s) {
        // phase a: issue x_{s+1} fetch (tag checked later; latency overlaps MFMAs)
        u64 v = 0; unsigned xr = 0;
        const bool wantx = (s + 1 < SEQ);
        const u64* pin = ring_in + ((size_t)((s + 1) % RD) * BB + rg * 16 + lm) * REL + ld;
        if (wantx) {
            if (l == 0) {
                if (ld < 50) {
                    const float2 t = *(const float2*)(noise + ((size_t)(s + 1) * BB + rg * 16 + lm) * KIN0 + 2 * ld);
                    xr = packh2(t.x, t.y);
                }
            } else {
                v = ald(pin);
            }
        }
        // backpressure: may we overwrite ring slot s%RD (holds step s-RD)?
        if (tid == 0 && !LAST && s >= RD) spinc(cons_my, (unsigned)(s - RD + 2));

        // phase b: x-part MFMAs (read u.x = x_s)
        f32x4 acc[2] = {{0, 0, 0, 0}, {0, 0, 0, 0}};
        #pragma unroll
        for (int q = 0; q < 4; ++q) {
            const f16x8 a = *(const f16x8*)(abase + 32 * q);
            acc[0] = __builtin_amdgcn_mfma_f32_16x16x32_f16(a, bf[0][q], acc[0], 0, 0, 0);
            acc[1] = __builtin_amdgcn_mfma_f32_16x16x32_f16(a, bf[1][q], acc[1], 0, 0, 0);
        }
        __syncthreads();   // barrier X: x_s reads done

        // phase e: h-part MFMAs (read u.h = h_{s-1})
        #pragma unroll
        for (int q = 4; q < 8; ++q) {
            const f16x8 a = *(const f16x8*)(abase + 32 * q);
            acc[0] = __builtin_amdgcn_mfma_f32_16x16x32_f16(a, bf[0][q], acc[0], 0, 0, 0);
            acc[1] = __builtin_amdgcn_mfma_f32_16x16x32_f16(a, bf[1][q], acc[1], 0, 0, 0);
        }
        // phase f: activation + gates to LDS. C map: row=4*kg+r, col=l16.
        #pragma unroll
        for (int t = 0; t < 2; ++t) {
            const int n = 16 * (2 * w + t) + l16;
            if (n < G4) {
                const bool istanh = (n >= 2 * H) && (n < 3 * H);
                #pragma unroll
                for (int r = 0; r < 4; ++r)
                    gl[(4 * kg + r) * GST + n] = act_gate(acc[t][r] + bias[t], istanh);
            }
        }
        // phase d: verify tag + install x_{s+1}
        if (wantx) {
            if (l > 0) {
                const unsigned expt = (unsigned)(s + 2);
                while ((unsigned)(v >> 32) != expt) { __builtin_amdgcn_s_sleep(1); v = ald(pin); }
                xr = (unsigned)v;
            }
            ((unsigned*)su)[lm * 132 + ld] = xr;
        }
        __syncthreads();   // barrier G: gates + x install + h reads done

        // phase h: state update + publish (tagged relaxed u64 stores)
        if (tid < 848) {
            const float* gm = gl + um * GST;
            const float i0 = gm[2 * up],         i1 = gm[2 * up + 1];
            const float f0 = gm[H + 2 * up],     f1 = gm[H + 2 * up + 1];
            const float g0 = gm[2 * H + 2 * up], g1 = gm[2 * H + 2 * up + 1];
            const float o0 = gm[3 * H + 2 * up], o1 = gm[3 * H + 2 * up + 1];
            c0 = fmaf(f0, c0, i0 * g0);
            c1 = fmaf(f1, c1, i1 * g1);
            const float h0 = o0 * fast_tanh(c0);
            const float h1 = o1 * fast_tanh(c1);
            const unsigned hw = packh2(h0, h1);
            ((unsigned*)su)[um * 132 + 64 + up] = hw;
            if (LAST) {
                *(float2*)(yout + ((size_t)s * BB + rg * 16 + um) * H + 2 * up) =
                    make_float2(h0, h1);
            } else {
                ast(ring_out + ((size_t)(s % RD) * BB + rg * 16 + um) * REL + up,
                    ((u64)(unsigned)(s + 1) << 32) | hw);
            }
        } else if (!LAST) {   // pad elements 53..55 (cols 106..111) = 0, tagged
            const int t2 = tid - 848, m = t2 / 3, dd = t2 % 3;
            ast(ring_out + ((size_t)(s % RD) * BB + rg * 16 + m) * REL + 53 + dd,
                (u64)(unsigned)(s + 1) << 32);
        }
        __syncthreads();   // barrier U: u=[x_{s+1}|h_s] complete

        if (tid == 0 && l > 0 && s + 1 < SEQ)
            __hip_atomic_store(cons_in, (unsigned)(s + 2),
                               __ATOMIC_RELAXED, __HIP_MEMORY_SCOPE_AGENT);
    }
}
}  // namespace

extern "C" void kernel_launch(void* const* d_in, const int* in_sizes, int n_in,
                              void* d_out, int out_size, void* d_ws, size_t ws_size,
                              hipStream_t stream) {
    const float* noise = (const float*)d_in[0];
    const float* W_ih0 = (const float*)d_in[1];
    const float* W_hh0 = (const float*)d_in[2];
    const float* b_ih0 = (const float*)d_in[3];
    const float* b_hh0 = (const float*)d_in[4];
    const float* W_ih  = (const float*)d_in[5];
    const float* W_hh  = (const float*)d_in[6];
    const float* b_ih  = (const float*)d_in[7];
    const float* b_hh  = (const float*)d_in[8];

    // clear counters + rings each call (kills stale tags across graph replays)
    const size_t clear_bytes = RING_OFF_B + (size_t)NLAYER * RING_PER_L * sizeof(u64);
    hipMemsetAsync(d_ws, 0, clear_bytes, stream);

    unsigned* cnt = (unsigned*)d_ws;
    u64* ring = (u64*)((char*)d_ws + RING_OFF_B);

    lstm_wave<<<dim3(NLAYER * RGN), dim3(NTHR), 0, stream>>>(
        noise, (float*)d_out, cnt, ring,
        W_ih0, W_hh0, b_ih0, b_hh0, W_ih, W_hh, b_ih, b_hh);
}

// Round 10
// 1419.065 us; speedup vs baseline: 8.2470x; 1.0403x over previous
//
#include <hip/hip_runtime.h>
#include <cmath>

// R10: wavefront LSTM, per-step latency taxes removed.
// vs R9 (1476us, T_step~2.9us):
//  - backpressure counter poll amortized: RD 8->16, check 1/8 steps (was a
//    ~900cyc IC load serialized at a barrier EVERY step)
//  - barrier X dropped via x double-buffer in LDS (2 barriers/step, not 3)
//  - gate reads as float2 (ds_read_b64, fewer LDS instrs + conflicts)
// Compute structure / fragment maps / tagged relaxed handoff: R8/R9-validated.

namespace {
constexpr int H = 106, G4 = 424, SEQ = 512, BB = 256, KIN0 = 100;
constexpr int UST = 392;            // su row stride (f16) = 196 dwords
constexpr int GST = 436;            // gates row stride (f32)
constexpr int NTHR = 896;           // 14 waves
constexpr int RGN = 16;             // rowgroups (16 rows each)
constexpr int NLAYER = 11;
constexpr int RD = 16;              // ring depth (steps)
constexpr int REL = 56;             // u64 elements per ring row
constexpr size_t CNT_STRIDE = 16;   // dwords per counter (64B)
constexpr size_t RING_OFF_B = 65536;
constexpr size_t RING_PER_L = (size_t)RD * BB * REL;   // u64 elements

using f16x8 = __attribute__((ext_vector_type(8))) _Float16;
using f32x4 = __attribute__((ext_vector_type(4))) float;
typedef unsigned long long u64;

__device__ __forceinline__ u64 ald(const u64* p) {
    return __hip_atomic_load(p, __ATOMIC_RELAXED, __HIP_MEMORY_SCOPE_AGENT);
}
__device__ __forceinline__ void ast(u64* p, u64 v) {
    __hip_atomic_store(p, v, __ATOMIC_RELAXED, __HIP_MEMORY_SCOPE_AGENT);
}
__device__ __forceinline__ void spinc(const unsigned* p, unsigned tgt) {
    while (__hip_atomic_load(p, __ATOMIC_RELAXED, __HIP_MEMORY_SCOPE_AGENT) < tgt)
        __builtin_amdgcn_s_sleep(8);
}
__device__ __forceinline__ float fast_tanh(float x) {
    float t = __expf(2.0f * x);
    return 1.0f - 2.0f / (t + 1.0f);
}
__device__ __forceinline__ float act_gate(float g, bool istanh) {
    float s = istanh ? 2.0f * g : g;
    float r = 1.0f / (1.0f + __expf(-s));
    return istanh ? 2.0f * r - 1.0f : r;
}
__device__ __forceinline__ unsigned packh2(float a, float b) {
    unsigned lo = (unsigned)__builtin_bit_cast(unsigned short, (_Float16)a);
    unsigned hi = (unsigned)__builtin_bit_cast(unsigned short, (_Float16)b);
    return (hi << 16) | lo;
}

__global__ __launch_bounds__(NTHR)
__attribute__((amdgpu_waves_per_eu(4, 4)))
void lstm_wave(const float* __restrict__ noise,   // (512,256,100) f32
               float* __restrict__ yout,          // (512,256,106) f32
               unsigned* cnt, u64* ring,
               const float* __restrict__ W_ih0, const float* __restrict__ W_hh0,
               const float* __restrict__ b_ih0, const float* __restrict__ b_hh0,
               const float* __restrict__ W_ih,  const float* __restrict__ W_hh,
               const float* __restrict__ b_ih,  const float* __restrict__ b_hh)
{
    const int l = blockIdx.x / RGN;
    const int rg = blockIdx.x % RGN;
    const bool LAST = (l == NLAYER - 1);
    const int K_IN = (l == 0) ? KIN0 : H;

    const float* Wih = (l == 0) ? W_ih0 : W_ih + (size_t)(l - 1) * G4 * H;
    const float* Whh = (l == 0) ? W_hh0 : W_hh + (size_t)(l - 1) * G4 * H;
    const float* pbi = (l == 0) ? b_ih0 : b_ih + (size_t)(l - 1) * G4;
    const float* pbh = (l == 0) ? b_hh0 : b_hh + (size_t)(l - 1) * G4;

    unsigned* cons_my = cnt + (size_t)(l * RGN + rg) * CNT_STRIDE;
    unsigned* cons_in = cnt + (size_t)((l - 1) * RGN + rg) * CNT_STRIDE;
    u64* ring_in  = ring + (size_t)(l - 1) * RING_PER_L;
    u64* ring_out = ring + (size_t)l * RING_PER_L;

    // su row: [x_slot0:0..127 | x_slot1:128..255 | h:256..361 | pad..391] f16
    __shared__ __align__(16) _Float16 su[16 * UST];
    __shared__ float gl[16 * GST];

    const int tid = threadIdx.x;
    const int w = tid >> 6, lane = tid & 63;
    const int l16 = lane & 15, kg = lane >> 4;
    const int lm = tid / 56, ld = tid % 56;   // loader map (row, element)

    // ---- weights: 2 N-tiles/wave, 8 k-steps (validated R8/R9) ----
    f16x8 bf[2][8];
    float bias[2];
    #pragma unroll
    for (int t = 0; t < 2; ++t) {
        const int n = 16 * (2 * w + t) + l16;
        const bool valid = n < G4;
        const float* pwx = Wih + (size_t)(valid ? n : 0) * K_IN;
        const float* pwh = Whh + (size_t)(valid ? n : 0) * H;
        #pragma unroll
        for (int q = 0; q < 8; ++q) {
            f16x8 v;
            #pragma unroll
            for (int e = 0; e < 8; ++e) {
                const int k = 32 * q + 8 * kg + e;
                float f = 0.0f;
                if (valid) {
                    if (k < 128) { if (k < K_IN) f = pwx[k]; }
                    else { const int kh = k - 128; if (kh < H) f = pwh[kh]; }
                }
                v[e] = (_Float16)f;
            }
            bf[t][q] = v;
        }
        bias[t] = valid ? (pbi[n] + pbh[n]) : 0.0f;
    }

    // ---- init: zero su, fetch x_0 into x slot 0 (tag 1) ----
    for (int i = tid; i < 16 * (UST / 2); i += NTHR) ((unsigned*)su)[i] = 0;
    float c0 = 0.0f, c1 = 0.0f;
    __syncthreads();
    {
        unsigned xr = 0;
        if (l == 0) {
            if (ld < 50) {
                const float2 v = *(const float2*)(noise + ((size_t)rg * 16 + lm) * KIN0 + 2 * ld);
                xr = packh2(v.x, v.y);
            }
        } else {
            const u64* p = ring_in + ((size_t)0 * BB + rg * 16 + lm) * REL + ld;
            u64 v = ald(p);
            while ((unsigned)(v >> 32) != 1u) { __builtin_amdgcn_s_sleep(1); v = ald(p); }
            xr = (unsigned)v;
        }
        ((unsigned*)su)[lm * 196 + ld] = xr;
    }
    __syncthreads();

    const int um = tid / 53, up = tid % 53;   // update map (row, H-pair)

    for (int s = 0; s < SEQ; ++s) {
        // phase a: issue x_{s+1} fetch (checked in phase d)
        u64 v = 0; unsigned xr = 0;
        const bool wantx = (s + 1 < SEQ);
        const u64* pin = ring_in + ((size_t)((s + 1) % RD) * BB + rg * 16 + lm) * REL + ld;
        if (wantx) {
            if (l == 0) {
                if (ld < 50) {
                    const float2 t = *(const float2*)(noise + ((size_t)(s + 1) * BB + rg * 16 + lm) * KIN0 + 2 * ld);
                    xr = packh2(t.x, t.y);
                }
            } else {
                v = ald(pin);
            }
        }
        // backpressure, batched 1/8 steps: writes s..s+7 overwrite s-16..s-9;
        // need consumed >= s-9  <=>  cons >= s-8.
        if (tid == 0 && !LAST && s >= RD && (s & 7) == 0)
            spinc(cons_my, (unsigned)(s - 8));

        // phase b: x-part MFMAs (read x slot s&1)
        const _Float16* arow = su + (size_t)l16 * UST;
        const _Float16* ax = arow + (s & 1) * 128 + 8 * kg;
        f32x4 acc[2] = {{0, 0, 0, 0}, {0, 0, 0, 0}};
        #pragma unroll
        for (int q = 0; q < 4; ++q) {
            const f16x8 a = *(const f16x8*)(ax + 32 * q);
            acc[0] = __builtin_amdgcn_mfma_f32_16x16x32_f16(a, bf[0][q], acc[0], 0, 0, 0);
            acc[1] = __builtin_amdgcn_mfma_f32_16x16x32_f16(a, bf[1][q], acc[1], 0, 0, 0);
        }
        // phase e: h-part MFMAs (read u.h = h_{s-1})
        const _Float16* ah = arow + 256 + 8 * kg;
        #pragma unroll
        for (int q = 4; q < 8; ++q) {
            const f16x8 a = *(const f16x8*)(ah + 32 * (q - 4));
            acc[0] = __builtin_amdgcn_mfma_f32_16x16x32_f16(a, bf[0][q], acc[0], 0, 0, 0);
            acc[1] = __builtin_amdgcn_mfma_f32_16x16x32_f16(a, bf[1][q], acc[1], 0, 0, 0);
        }
        // phase f: activation + gates to LDS. C map: row=4*kg+r, col=l16.
        #pragma unroll
        for (int t = 0; t < 2; ++t) {
            const int n = 16 * (2 * w + t) + l16;
            if (n < G4) {
                const bool istanh = (n >= 2 * H) && (n < 3 * H);
                #pragma unroll
                for (int r = 0; r < 4; ++r)
                    gl[(4 * kg + r) * GST + n] = act_gate(acc[t][r] + bias[t], istanh);
            }
        }
        // phase d: verify tag + install x_{s+1} into slot (s+1)&1
        if (wantx) {
            if (l > 0) {
                const unsigned expt = (unsigned)(s + 2);
                while ((unsigned)(v >> 32) != expt) { __builtin_amdgcn_s_sleep(1); v = ald(pin); }
                xr = (unsigned)v;
            }
            ((unsigned*)su)[lm * 196 + ((s + 1) & 1) * 64 + ld] = xr;
        }
        __syncthreads();   // barrier G: gates + x install + h reads done

        // phase h: state update + publish
        if (tid < 848) {
            const float* gm = gl + um * GST;
            const float2 vi = *(const float2*)(gm + 2 * up);
            const float2 vf = *(const float2*)(gm + H + 2 * up);
            const float2 vg = *(const float2*)(gm + 2 * H + 2 * up);
            const float2 vo = *(const float2*)(gm + 3 * H + 2 * up);
            c0 = fmaf(vf.x, c0, vi.x * vg.x);
            c1 = fmaf(vf.y, c1, vi.y * vg.y);
            const float h0 = vo.x * fast_tanh(c0);
            const float h1 = vo.y * fast_tanh(c1);
            const unsigned hw = packh2(h0, h1);
            ((unsigned*)su)[um * 196 + 128 + up] = hw;
            if (LAST) {
                *(float2*)(yout + ((size_t)s * BB + rg * 16 + um) * H + 2 * up) =
                    make_float2(h0, h1);
            } else {
                ast(ring_out + ((size_t)(s % RD) * BB + rg * 16 + um) * REL + up,
                    ((u64)(unsigned)(s + 1) << 32) | hw);
            }
        } else if (!LAST) {   // pad elements 53..55 = 0, tagged
            const int t2 = tid - 848, m = t2 / 3, dd = t2 % 3;
            ast(ring_out + ((size_t)(s % RD) * BB + rg * 16 + m) * REL + 53 + dd,
                (u64)(unsigned)(s + 1) << 32);
        }
        __syncthreads();   // barrier U: h_s + ring writes complete

        if (tid == 0 && l > 0 && s + 1 < SEQ)
            __hip_atomic_store(cons_in, (unsigned)(s + 2),
                               __ATOMIC_RELAXED, __HIP_MEMORY_SCOPE_AGENT);
    }
}
}  // namespace

extern "C" void kernel_launch(void* const* d_in, const int* in_sizes, int n_in,
                              void* d_out, int out_size, void* d_ws, size_t ws_size,
                              hipStream_t stream) {
    const float* noise = (const float*)d_in[0];
    const float* W_ih0 = (const float*)d_in[1];
    const float* W_hh0 = (const float*)d_in[2];
    const float* b_ih0 = (const float*)d_in[3];
    const float* b_hh0 = (const float*)d_in[4];
    const float* W_ih  = (const float*)d_in[5];
    const float* W_hh  = (const float*)d_in[6];
    const float* b_ih  = (const float*)d_in[7];
    const float* b_hh  = (const float*)d_in[8];

    // clear counters + rings each call (replay-safe)
    const size_t clear_bytes = RING_OFF_B + (size_t)NLAYER * RING_PER_L * sizeof(u64);
    hipMemsetAsync(d_ws, 0, clear_bytes, stream);

    unsigned* cnt = (unsigned*)d_ws;
    u64* ring = (u64*)((char*)d_ws + RING_OFF_B);

    lstm_wave<<<dim3(NLAYER * RGN), dim3(NTHR), 0, stream>>>(
        noise, (float*)d_out, cnt, ring,
        W_ih0, W_hh0, b_ih0, b_hh0, W_ih, W_hh, b_ih, b_hh);
}

// Round 11
// 1351.806 us; speedup vs baseline: 8.6573x; 1.0498x over previous
//
#include <hip/hip_runtime.h>
#include <cmath>

// R11: wavefront LSTM. vs R10:
//  - x-part MFMAs hoisted OFF the loop-carried chain: accx(s+1) computed
//    between barriers G and U of step s; h-chain at s+1 starts from C=accx.
//    (Same accumulation order as before -> bitwise-identical numerics.)
//  - 2-step-ahead ring prefetch: load x_{s+2} issued at step s, tag-checked
//    at step s+1 -> steady-state polls hit first try.
// All fragment maps / handoff / backpressure: R8-R10 validated.

namespace {
constexpr int H = 106, G4 = 424, SEQ = 512, BB = 256, KIN0 = 100;
constexpr int UST = 392;            // su row stride (f16) = 196 dwords
constexpr int GST = 436;            // gates row stride (f32)
constexpr int NTHR = 896;           // 14 waves
constexpr int RGN = 16;             // rowgroups (16 rows each)
constexpr int NLAYER = 11;
constexpr int RD = 16;              // ring depth (steps)
constexpr int REL = 56;             // u64 elements per ring row
constexpr size_t CNT_STRIDE = 16;   // dwords per counter (64B)
constexpr size_t RING_OFF_B = 65536;
constexpr size_t RING_PER_L = (size_t)RD * BB * REL;   // u64 elements

using f16x8 = __attribute__((ext_vector_type(8))) _Float16;
using f32x4 = __attribute__((ext_vector_type(4))) float;
typedef unsigned long long u64;

__device__ __forceinline__ u64 ald(const u64* p) {
    return __hip_atomic_load(p, __ATOMIC_RELAXED, __HIP_MEMORY_SCOPE_AGENT);
}
__device__ __forceinline__ void ast(u64* p, u64 v) {
    __hip_atomic_store(p, v, __ATOMIC_RELAXED, __HIP_MEMORY_SCOPE_AGENT);
}
__device__ __forceinline__ void spinc(const unsigned* p, unsigned tgt) {
    while (__hip_atomic_load(p, __ATOMIC_RELAXED, __HIP_MEMORY_SCOPE_AGENT) < tgt)
        __builtin_amdgcn_s_sleep(8);
}
__device__ __forceinline__ float fast_tanh(float x) {
    float t = __expf(2.0f * x);
    return 1.0f - 2.0f / (t + 1.0f);
}
__device__ __forceinline__ float act_gate(float g, bool istanh) {
    float s = istanh ? 2.0f * g : g;
    float r = 1.0f / (1.0f + __expf(-s));
    return istanh ? 2.0f * r - 1.0f : r;
}
__device__ __forceinline__ unsigned packh2(float a, float b) {
    unsigned lo = (unsigned)__builtin_bit_cast(unsigned short, (_Float16)a);
    unsigned hi = (unsigned)__builtin_bit_cast(unsigned short, (_Float16)b);
    return (hi << 16) | lo;
}

__global__ __launch_bounds__(NTHR)
__attribute__((amdgpu_waves_per_eu(4, 4)))
void lstm_wave(const float* __restrict__ noise,   // (512,256,100) f32
               float* __restrict__ yout,          // (512,256,106) f32
               unsigned* cnt, u64* ring,
               const float* __restrict__ W_ih0, const float* __restrict__ W_hh0,
               const float* __restrict__ b_ih0, const float* __restrict__ b_hh0,
               const float* __restrict__ W_ih,  const float* __restrict__ W_hh,
               const float* __restrict__ b_ih,  const float* __restrict__ b_hh)
{
    const int l = blockIdx.x / RGN;
    const int rg = blockIdx.x % RGN;
    const bool LAST = (l == NLAYER - 1);
    const int K_IN = (l == 0) ? KIN0 : H;

    const float* Wih = (l == 0) ? W_ih0 : W_ih + (size_t)(l - 1) * G4 * H;
    const float* Whh = (l == 0) ? W_hh0 : W_hh + (size_t)(l - 1) * G4 * H;
    const float* pbi = (l == 0) ? b_ih0 : b_ih + (size_t)(l - 1) * G4;
    const float* pbh = (l == 0) ? b_hh0 : b_hh + (size_t)(l - 1) * G4;

    unsigned* cons_my = cnt + (size_t)(l * RGN + rg) * CNT_STRIDE;
    unsigned* cons_in = cnt + (size_t)((l - 1) * RGN + rg) * CNT_STRIDE;
    u64* ring_in  = ring + (size_t)(l - 1) * RING_PER_L;
    u64* ring_out = ring + (size_t)l * RING_PER_L;

    // su row: [x_slot0:0..127 | x_slot1:128..255 | h:256..361 | pad..391] f16
    __shared__ __align__(16) _Float16 su[16 * UST];
    __shared__ float gl[16 * GST];

    const int tid = threadIdx.x;
    const int w = tid >> 6, lane = tid & 63;
    const int l16 = lane & 15, kg = lane >> 4;
    const int lm = tid / 56, ld = tid % 56;   // loader map (row, element)

    // ---- weights: 2 N-tiles/wave, 8 k-steps (validated R8-R10) ----
    f16x8 bf[2][8];
    float bias[2];
    #pragma unroll
    for (int t = 0; t < 2; ++t) {
        const int n = 16 * (2 * w + t) + l16;
        const bool valid = n < G4;
        const float* pwx = Wih + (size_t)(valid ? n : 0) * K_IN;
        const float* pwh = Whh + (size_t)(valid ? n : 0) * H;
        #pragma unroll
        for (int q = 0; q < 8; ++q) {
            f16x8 v;
            #pragma unroll
            for (int e = 0; e < 8; ++e) {
                const int k = 32 * q + 8 * kg + e;
                float f = 0.0f;
                if (valid) {
                    if (k < 128) { if (k < K_IN) f = pwx[k]; }
                    else { const int kh = k - 128; if (kh < H) f = pwh[kh]; }
                }
                v[e] = (_Float16)f;
            }
            bf[t][q] = v;
        }
        bias[t] = valid ? (pbi[n] + pbh[n]) : 0.0f;
    }

    // ---- init: zero su, fetch x_0 into x slot 0 (tag 1) ----
    for (int i = tid; i < 16 * (UST / 2); i += NTHR) ((unsigned*)su)[i] = 0;
    float c0 = 0.0f, c1 = 0.0f;
    __syncthreads();
    {
        unsigned xr = 0;
        if (l == 0) {
            if (ld < 50) {
                const float2 v = *(const float2*)(noise + ((size_t)rg * 16 + lm) * KIN0 + 2 * ld);
                xr = packh2(v.x, v.y);
            }
        } else {
            const u64* p = ring_in + ((size_t)0 * BB + rg * 16 + lm) * REL + ld;
            u64 v = ald(p);
            while ((unsigned)(v >> 32) != 1u) { __builtin_amdgcn_s_sleep(1); v = ald(p); }
            xr = (unsigned)v;
        }
        ((unsigned*)su)[lm * 196 + ld] = xr;
    }
    __syncthreads();

    const int um = tid / 53, up = tid % 53;   // update map (row, H-pair)
    const _Float16* arow = su + (size_t)l16 * UST;

    // ---- prelude: accx for s=0 (x slot 0); issue ring load for x_1 ----
    f32x4 accx[2] = {{0, 0, 0, 0}, {0, 0, 0, 0}};
    {
        const _Float16* ax = arow + 8 * kg;
        #pragma unroll
        for (int q = 0; q < 4; ++q) {
            const f16x8 a = *(const f16x8*)(ax + 32 * q);
            accx[0] = __builtin_amdgcn_mfma_f32_16x16x32_f16(a, bf[0][q], accx[0], 0, 0, 0);
            accx[1] = __builtin_amdgcn_mfma_f32_16x16x32_f16(a, bf[1][q], accx[1], 0, 0, 0);
        }
    }
    u64 vprev = 0;   // in-flight ring word for x_{s+1}
    if (l > 0) vprev = ald(ring_in + ((size_t)(1 % RD) * BB + rg * 16 + lm) * REL + ld);

    for (int s = 0; s < SEQ; ++s) {
        // phase a: issue ring load for x_{s+2}; l==0 loads noise for x_{s+1}
        u64 vnext = 0; unsigned xr = 0;
        const bool wantx = (s + 1 < SEQ);
        if (l > 0) {
            if (s + 2 < SEQ)
                vnext = ald(ring_in + ((size_t)((s + 2) % RD) * BB + rg * 16 + lm) * REL + ld);
        } else if (wantx && ld < 50) {
            const float2 t = *(const float2*)(noise + ((size_t)(s + 1) * BB + rg * 16 + lm) * KIN0 + 2 * ld);
            xr = packh2(t.x, t.y);
        }
        // backpressure, batched 1/8 steps
        if (tid == 0 && !LAST && s >= RD && (s & 7) == 0)
            spinc(cons_my, (unsigned)(s - 8));

        // phase e: h-part MFMAs (C init = accx from previous step's phase i)
        f32x4 acc[2] = {accx[0], accx[1]};
        const _Float16* ah = arow + 256 + 8 * kg;
        #pragma unroll
        for (int q = 4; q < 8; ++q) {
            const f16x8 a = *(const f16x8*)(ah + 32 * (q - 4));
            acc[0] = __builtin_amdgcn_mfma_f32_16x16x32_f16(a, bf[0][q], acc[0], 0, 0, 0);
            acc[1] = __builtin_amdgcn_mfma_f32_16x16x32_f16(a, bf[1][q], acc[1], 0, 0, 0);
        }
        // phase f: activation + gates to LDS. C map: row=4*kg+r, col=l16.
        #pragma unroll
        for (int t = 0; t < 2; ++t) {
            const int n = 16 * (2 * w + t) + l16;
            if (n < G4) {
                const bool istanh = (n >= 2 * H) && (n < 3 * H);
                #pragma unroll
                for (int r = 0; r < 4; ++r)
                    gl[(4 * kg + r) * GST + n] = act_gate(acc[t][r] + bias[t], istanh);
            }
        }
        // phase d: verify tag of x_{s+1} + install into slot (s+1)&1
        if (wantx) {
            if (l > 0) {
                const unsigned expt = (unsigned)(s + 2);
                const u64* pin = ring_in + ((size_t)((s + 1) % RD) * BB + rg * 16 + lm) * REL + ld;
                while ((unsigned)(vprev >> 32) != expt) { __builtin_amdgcn_s_sleep(1); vprev = ald(pin); }
                xr = (unsigned)vprev;
            }
            ((unsigned*)su)[lm * 196 + ((s + 1) & 1) * 64 + ld] = xr;
        }
        vprev = vnext;
        __syncthreads();   // barrier G: gates + x_{s+1} install + h reads done

        // phase h: state update + publish
        if (tid < 848) {
            const float* gm = gl + um * GST;
            const float2 vi = *(const float2*)(gm + 2 * up);
            const float2 vf = *(const float2*)(gm + H + 2 * up);
            const float2 vg = *(const float2*)(gm + 2 * H + 2 * up);
            const float2 vo = *(const float2*)(gm + 3 * H + 2 * up);
            c0 = fmaf(vf.x, c0, vi.x * vg.x);
            c1 = fmaf(vf.y, c1, vi.y * vg.y);
            const float h0 = vo.x * fast_tanh(c0);
            const float h1 = vo.y * fast_tanh(c1);
            const unsigned hw = packh2(h0, h1);
            ((unsigned*)su)[um * 196 + 128 + up] = hw;
            if (LAST) {
                *(float2*)(yout + ((size_t)s * BB + rg * 16 + um) * H + 2 * up) =
                    make_float2(h0, h1);
            } else {
                ast(ring_out + ((size_t)(s % RD) * BB + rg * 16 + um) * REL + up,
                    ((u64)(unsigned)(s + 1) << 32) | hw);
            }
        } else if (!LAST) {   // pad elements 53..55 = 0, tagged
            const int t2 = tid - 848, m = t2 / 3, dd = t2 % 3;
            ast(ring_out + ((size_t)(s % RD) * BB + rg * 16 + m) * REL + 53 + dd,
                (u64)(unsigned)(s + 1) << 32);
        }
        // phase i: x-part MFMAs for step s+1 (off the h critical chain)
        if (wantx) {
            const _Float16* ax = arow + ((s + 1) & 1) * 128 + 8 * kg;
            accx[0] = f32x4{0, 0, 0, 0};
            accx[1] = f32x4{0, 0, 0, 0};
            #pragma unroll
            for (int q = 0; q < 4; ++q) {
                const f16x8 a = *(const f16x8*)(ax + 32 * q);
                accx[0] = __builtin_amdgcn_mfma_f32_16x16x32_f16(a, bf[0][q], accx[0], 0, 0, 0);
                accx[1] = __builtin_amdgcn_mfma_f32_16x16x32_f16(a, bf[1][q], accx[1], 0, 0, 0);
            }
        }
        __syncthreads();   // barrier U: h_s + ring writes + accx complete

        if (tid == 0 && l > 0 && s + 1 < SEQ)
            __hip_atomic_store(cons_in, (unsigned)(s + 2),
                               __ATOMIC_RELAXED, __HIP_MEMORY_SCOPE_AGENT);
    }
}
}  // namespace

extern "C" void kernel_launch(void* const* d_in, const int* in_sizes, int n_in,
                              void* d_out, int out_size, void* d_ws, size_t ws_size,
                              hipStream_t stream) {
    const float* noise = (const float*)d_in[0];
    const float* W_ih0 = (const float*)d_in[1];
    const float* W_hh0 = (const float*)d_in[2];
    const float* b_ih0 = (const float*)d_in[3];
    const float* b_hh0 = (const float*)d_in[4];
    const float* W_ih  = (const float*)d_in[5];
    const float* W_hh  = (const float*)d_in[6];
    const float* b_ih  = (const float*)d_in[7];
    const float* b_hh  = (const float*)d_in[8];

    // clear counters + rings each call (replay-safe)
    const size_t clear_bytes = RING_OFF_B + (size_t)NLAYER * RING_PER_L * sizeof(u64);
    hipMemsetAsync(d_ws, 0, clear_bytes, stream);

    unsigned* cnt = (unsigned*)d_ws;
    u64* ring = (u64*)((char*)d_ws + RING_OFF_B);

    lstm_wave<<<dim3(NLAYER * RGN), dim3(NTHR), 0, stream>>>(
        noise, (float*)d_out, cnt, ring,
        W_ih0, W_hh0, b_ih0, b_hh0, W_ih, W_hh, b_ih, b_hh);
}